// Round 9
// baseline (346.173 us; speedup 1.0000x reference)
//
#include <hip/hip_runtime.h>
#include <hip/hip_bf16.h>
#include <hip/hip_fp16.h>

#define N_NODES 100000
#define N_EDGES 1600000
#define IN_DIM 128
#define C1 256      // HEADS*HID = 4*64
#define HID 64
#define HEADS 4
#define OUT_DIM 32
#define SLOPE 0.2f

// bucketed CSR build params
#define NCHUNK 256
#define CHUNK_E ((N_EDGES + NCHUNK - 1) / NCHUNK)  // 6250
#define NBKT 1024        // buckets of 128 nodes (782 used)
#define BSH 7
#define NBKT_USED ((N_NODES + 127) >> 7)  // 782

typedef _Float16 f16x8 __attribute__((ext_vector_type(8)));
typedef float f32x4 __attribute__((ext_vector_type(4)));

__device__ __forceinline__ float leaky(float t) { return t > 0.f ? t : SLOPE * t; }

__device__ __forceinline__ float sel4(float a, float b, float c, float d, int k) {
    float lo = (k & 1) ? b : a;
    float hi = (k & 1) ? d : c;
    return (k & 2) ? hi : lo;
}

// ---------------- bucketed CSR build (LDS atomics only) ----------------
// partT[bucket][chunk]: written strided here, read contiguously in k_bscan.
// blocks >= NCHUNK handle the W1/W2 fragment repack (fused to save a dispatch).
__global__ void k_bhist(const int* __restrict__ dst, int* __restrict__ partT,
                        const float* __restrict__ W1, const float* __restrict__ W2,
                        f16x8* __restrict__ o1, f16x8* __restrict__ o2) {
    int blk = blockIdx.x, tid = threadIdx.x;
    if (blk >= NCHUNK) {
        int t = (blk - NCHUNK) * 256 + tid;
        if (t < 4096) {
            int kc = t >> 10, c = (t >> 6) & 15, lane = t & 63;
            int k0 = kc * 32 + ((lane >> 4) << 3), nn = c * 16 + (lane & 15);
            f16x8 r;
#pragma unroll
            for (int v = 0; v < 8; v++) r[v] = (_Float16)W1[(k0 + v) * 256 + nn];
            o1[t] = r;
        } else if (t < 5120) {
            int u = t - 4096;
            int kc = u >> 7, c = (u >> 6) & 1, lane = u & 63;
            int k0 = kc * 32 + ((lane >> 4) << 3), nn = c * 16 + (lane & 15);
            f16x8 r;
#pragma unroll
            for (int v = 0; v < 8; v++) r[v] = (_Float16)W2[(k0 + v) * 32 + nn];
            o2[u] = r;
        }
        return;
    }
    __shared__ int h[NBKT];
    for (int i = tid; i < NBKT; i += 256) h[i] = 0;
    __syncthreads();
    int e0 = blk * CHUNK_E;
    int e1 = e0 + CHUNK_E;
    if (e1 > N_EDGES) e1 = N_EDGES;
    for (int i = e0 + tid; i < e1; i += 256) atomicAdd(&h[dst[i] >> BSH], 1);
    __syncthreads();
    for (int i = tid; i < NBKT; i += 256) partT[i * NCHUNK + blk] = h[i];
}

// single block, 1024 threads; all global accesses contiguous per thread now
__global__ void k_bscan(const int* __restrict__ partT, int* __restrict__ part2,
                        int* __restrict__ bucket_base, int* __restrict__ row_ptr_last) {
    __shared__ int sm[NBKT];
    int b = threadIdx.x;
    int tot = 0;
    for (int c = 0; c < NCHUNK; c += 4) {
        int4 v = *(const int4*)(partT + b * NCHUNK + c);
        tot += v.x + v.y + v.z + v.w;
    }
    sm[b] = tot;
    __syncthreads();
    for (int off = 1; off < NBKT; off <<= 1) {
        int u = (b >= off) ? sm[b - off] : 0;
        __syncthreads();
        sm[b] += u;
        __syncthreads();
    }
    int incl = sm[b], excl = incl - tot;
    bucket_base[b] = excl;
    if (b == NBKT - 1) {
        bucket_base[NBKT] = incl;
        *row_ptr_last = incl;  // row_ptr[N] = E
    }
    int run = excl;
    for (int c = 0; c < NCHUNK; c++) {
        part2[c * NBKT + b] = run;               // strided store, fire-and-forget
        run += partT[b * NCHUNK + c];            // contiguous re-read (L2-hot)
    }
}

__global__ void k_bscatter(const int* __restrict__ src, const int* __restrict__ dst,
                           const int* __restrict__ part2, uint* __restrict__ ebuf) {
    __shared__ int cur[NBKT];
    int tid = threadIdx.x, blk = blockIdx.x;
    for (int i = tid; i < NBKT; i += 256) cur[i] = part2[blk * NBKT + i];
    __syncthreads();
    int e0 = blk * CHUNK_E;
    int e1 = e0 + CHUNK_E;
    if (e1 > N_EDGES) e1 = N_EDGES;
    for (int i = e0 + tid; i < e1; i += 256) {
        int d = dst[i];
        int b = d >> BSH;
        int pos = atomicAdd(&cur[b], 1);
        ebuf[pos] = (uint)src[i] | ((uint)(d & 127) << 20);
    }
}

__global__ void k_bsort(const uint* __restrict__ ebuf, const int* __restrict__ bucket_base,
                        int* __restrict__ row_ptr, int* __restrict__ col, int n) {
    __shared__ int h[128], sc[128], cur[128];
    int tid = threadIdx.x, b = blockIdx.x;
    int s0 = bucket_base[b], s1 = bucket_base[b + 1];
    if (tid < 128) h[tid] = 0;
    __syncthreads();
    for (int i = s0 + tid; i < s1; i += 256) atomicAdd(&h[ebuf[i] >> 20], 1);
    __syncthreads();
    if (tid < 128) sc[tid] = h[tid];
    __syncthreads();
    for (int off = 1; off < 128; off <<= 1) {
        int u = 0;
        if (tid < 128 && tid >= off) u = sc[tid - off];
        __syncthreads();
        if (tid < 128) sc[tid] += u;
        __syncthreads();
    }
    if (tid < 128) {
        int excl = sc[tid] - h[tid];
        cur[tid] = excl;
        int node = (b << BSH) + tid;
        if (node < n) row_ptr[node] = s0 + excl;
    }
    __syncthreads();
    for (int i = s0 + tid; i < s1; i += 256) {
        uint pk = ebuf[i];
        int f = pk >> 20;
        int pos = atomicAdd(&cur[f], 1);
        col[s0 + pos] = (int)(pk & 0xFFFFFu);
    }
}

// ---------------- GEMM1 (MFMA) + fused att1 ----------------
#define LDA 136
#define LDO 264
__launch_bounds__(256)
__global__ void k_gemm1(const float* __restrict__ x, const f16x8* __restrict__ Wfrag,
                        __half* __restrict__ h1h, const float* __restrict__ a_src,
                        const float* __restrict__ a_dst, float* __restrict__ es,
                        float* __restrict__ ed, int n) {
    __shared__ __align__(16) __half sm[64 * LDO];
    __shared__ float s_es[4][64], s_ed[4][64];
    int tid = threadIdx.x, lane = tid & 63, w = tid >> 6;
    int row0 = blockIdx.x * 64;

    f16x8 bf[4][4];
#pragma unroll
    for (int kc = 0; kc < 4; kc++)
#pragma unroll
        for (int cc = 0; cc < 4; cc++)
            bf[kc][cc] = Wfrag[(kc * 16 + w * 4 + cc) * 64 + lane];

    for (int i = tid; i < 64 * 32; i += 256) {
        int r = i >> 5, c4 = i & 31;
        float4 v = make_float4(0.f, 0.f, 0.f, 0.f);
        if (row0 + r < n) v = *(const float4*)(x + (size_t)(row0 + r) * 128 + c4 * 4);
        __half2 h0 = __halves2half2(__float2half(v.x), __float2half(v.y));
        __half2 h1 = __halves2half2(__float2half(v.z), __float2half(v.w));
        uint2 u;
        u.x = *(uint*)&h0;
        u.y = *(uint*)&h1;
        *(uint2*)(sm + r * LDA + c4 * 4) = u;
    }
    __syncthreads();

    f32x4 acc[4][4];
#pragma unroll
    for (int rf = 0; rf < 4; rf++)
#pragma unroll
        for (int cc = 0; cc < 4; cc++) acc[rf][cc] = (f32x4){0.f, 0.f, 0.f, 0.f};

#pragma unroll
    for (int kc = 0; kc < 4; kc++) {
        f16x8 af[4];
#pragma unroll
        for (int rf = 0; rf < 4; rf++) {
            int row = rf * 16 + (lane & 15);
            int koff = kc * 32 + ((lane >> 4) << 3);
            af[rf] = *(const f16x8*)(sm + row * LDA + koff);
        }
#pragma unroll
        for (int rf = 0; rf < 4; rf++)
#pragma unroll
            for (int cc = 0; cc < 4; cc++)
                acc[rf][cc] = __builtin_amdgcn_mfma_f32_16x16x32_f16(af[rf], bf[kc][cc],
                                                                     acc[rf][cc], 0, 0, 0);
    }
    __syncthreads();

#pragma unroll
    for (int rf = 0; rf < 4; rf++)
#pragma unroll
        for (int cc = 0; cc < 4; cc++) {
            int colp = w * 64 + cc * 16 + (lane & 15);
            int rb = rf * 16 + ((lane >> 4) << 2);
#pragma unroll
            for (int j = 0; j < 4; j++) sm[(rb + j) * LDO + colp] = __float2half(acc[rf][cc][j]);
        }
    __syncthreads();

    // fused att1: thread handles (row = tid&63, head q = tid>>6)
    {
        int row = tid & 63, q = w;
        float ps = 0.f, pd = 0.f;
        const __half* rp = sm + row * LDO + q * 64;
#pragma unroll
        for (int c4 = 0; c4 < 16; c4++) {
            uint2 u = *(const uint2*)(rp + c4 * 4);
            __half2 ha = *reinterpret_cast<__half2*>(&u.x);
            __half2 hb = *reinterpret_cast<__half2*>(&u.y);
            float v0 = __half2float(ha.x), v1 = __half2float(ha.y);
            float v2 = __half2float(hb.x), v3 = __half2float(hb.y);
            float4 av = *(const float4*)(a_src + q * 64 + c4 * 4);
            float4 dv = *(const float4*)(a_dst + q * 64 + c4 * 4);
            ps += v0 * av.x + v1 * av.y + v2 * av.z + v3 * av.w;
            pd += v0 * dv.x + v1 * dv.y + v2 * dv.z + v3 * dv.w;
        }
        s_es[q][row] = ps;
        s_ed[q][row] = pd;
    }

    for (int i = tid; i < 64 * 32; i += 256) {
        int r = i >> 5, cb = i & 31;
        if (row0 + r < n) {
            uint4 u = *(const uint4*)(sm + r * LDO + cb * 8);
            *(uint4*)(h1h + (size_t)(row0 + r) * 256 + cb * 8) = u;
        }
    }
    __syncthreads();
    if (tid < 64 && row0 + tid < n) {
        ((float4*)es)[row0 + tid] =
            make_float4(s_es[0][tid], s_es[1][tid], s_es[2][tid], s_es[3][tid]);
        ((float4*)ed)[row0 + tid] =
            make_float4(s_ed[0][tid], s_ed[1][tid], s_ed[2][tid], s_ed[3][tid]);
    }
}

// ---------------- layer1 aggregation: 32 lanes per node, 2 nodes per wave, 4-deep MLP ----------------
__launch_bounds__(256)
__global__ void k_aggr1(const __half* __restrict__ h1h, const float* __restrict__ es,
                        const float* __restrict__ ed, const int* __restrict__ row_ptr,
                        const int* __restrict__ col, const float* __restrict__ b,
                        __half* __restrict__ out1h, int n) {
    __shared__ int s_idx[4][64];
    __shared__ __align__(16) float s_al[4][256];
    int tid = threadIdx.x, lane = tid & 63, w = tid >> 6;
    int h = lane >> 5, l = lane & 31, k0 = l >> 3;
    int node = blockIdx.x * 8 + w * 2 + h;
    bool valid = node < n;
    int nodec = valid ? node : 0;

    float4 ed4 = ((const float4*)ed)[nodec];
    float4 es4 = ((const float4*)es)[nodec];
    float edk = sel4(ed4.x, ed4.y, ed4.z, ed4.w, k0);
    float esk = sel4(es4.x, es4.y, es4.z, es4.w, k0);

    uint4 sraw = *(const uint4*)(h1h + (size_t)nodec * 256 + l * 8);
    const __half2* sh = (const __half2*)&sraw;
    float tself = __expf(leaky(esk + edk));
    float acc[8];
#pragma unroll
    for (int i = 0; i < 4; i++) {
        acc[2 * i] = tself * __half2float(sh[i].x);
        acc[2 * i + 1] = tself * __half2float(sh[i].y);
    }
    float dl[4];
#pragma unroll
    for (int k = 0; k < 4; k++) dl[k] = 0.f;
    if (l == 0) {
        dl[0] = __expf(leaky(es4.x + ed4.x));
        dl[1] = __expf(leaky(es4.y + ed4.y));
        dl[2] = __expf(leaky(es4.z + ed4.z));
        dl[3] = __expf(leaky(es4.w + ed4.w));
    }

    int beg = valid ? row_ptr[nodec] : 0;
    int end = valid ? row_ptr[nodec + 1] : 0;
    int deg = end - beg;
    for (int base = 0;; base += 32) {
        int rem = deg - base;
        int nvh = rem > 32 ? 32 : rem;
        int nvo = __shfl_xor(nvh < 0 ? 0 : nvh, 32);
        int nvmax = nvh > nvo ? nvh : nvo;
        if (nvmax <= 0) break;
        int j = beg + base + l;
        int s = 0;
        float e0 = 0.f, e1 = 0.f, e2 = 0.f, e3 = 0.f;
        if (l < nvh) {
            s = col[j];
            float4 e4 = ((const float4*)es)[s];
            e0 = __expf(leaky(e4.x + ed4.x));
            e1 = __expf(leaky(e4.y + ed4.y));
            e2 = __expf(leaky(e4.z + ed4.z));
            e3 = __expf(leaky(e4.w + ed4.w));
            dl[0] += e0;
            dl[1] += e1;
            dl[2] += e2;
            dl[3] += e3;
        }
        s_idx[w][lane] = s;
        *(float4*)&s_al[w][lane * 4] = make_float4(e0, e1, e2, e3);
        int lbase = h << 5;
        // 4-deep batched gather: issue 4 independent loads before consuming
        for (int j2 = 0; j2 < nvmax; j2 += 4) {
            int sb[4];
            float ee[4];
#pragma unroll
            for (int u = 0; u < 4; u++) {
                int jj = j2 + u;
                bool v2 = jj < nvh;
                sb[u] = v2 ? s_idx[w][lbase + jj] : 0;
                ee[u] = v2 ? s_al[w][(lbase + jj) * 4 + k0] : 0.f;
            }
            uint4 rv0 = *(const uint4*)(h1h + (size_t)sb[0] * 256 + l * 8);
            uint4 rv1 = *(const uint4*)(h1h + (size_t)sb[1] * 256 + l * 8);
            uint4 rv2 = *(const uint4*)(h1h + (size_t)sb[2] * 256 + l * 8);
            uint4 rv3 = *(const uint4*)(h1h + (size_t)sb[3] * 256 + l * 8);
            uint4 rvs[4] = {rv0, rv1, rv2, rv3};
#pragma unroll
            for (int u = 0; u < 4; u++) {
                const __half2* hp = (const __half2*)&rvs[u];
                float e = ee[u];
#pragma unroll
                for (int i = 0; i < 4; i++) {
                    acc[2 * i] += e * __half2float(hp[i].x);
                    acc[2 * i + 1] += e * __half2float(hp[i].y);
                }
            }
        }
    }
#pragma unroll
    for (int off = 1; off < 32; off <<= 1) {
#pragma unroll
        for (int k = 0; k < 4; k++) dl[k] += __shfl_xor(dl[k], off);
    }
    float dlk = sel4(dl[0], dl[1], dl[2], dl[3], k0) + 1e-16f;
    float inv = 1.f / dlk;
    float4 b0 = *(const float4*)(b + l * 8);
    float4 b1 = *(const float4*)(b + l * 8 + 4);
    float o[8];
    o[0] = acc[0] * inv + b0.x;
    o[1] = acc[1] * inv + b0.y;
    o[2] = acc[2] * inv + b0.z;
    o[3] = acc[3] * inv + b0.w;
    o[4] = acc[4] * inv + b1.x;
    o[5] = acc[5] * inv + b1.y;
    o[6] = acc[6] * inv + b1.z;
    o[7] = acc[7] * inv + b1.w;
    uint4 pk;
    __half2* ph = (__half2*)&pk;
#pragma unroll
    for (int i = 0; i < 4; i++) {
        float a0 = o[2 * i], a1 = o[2 * i + 1];
        a0 = a0 > 0.f ? a0 : __expf(a0) - 1.f;
        a1 = a1 > 0.f ? a1 : __expf(a1) - 1.f;
        ph[i] = __halves2half2(__float2half(a0), __float2half(a1));
    }
    if (valid) *(uint4*)(out1h + (size_t)node * 256 + l * 8) = pk;
}

// ---------------- GEMM2 (MFMA) + fused att2 ----------------
#define LDA2 264
__launch_bounds__(256)
__global__ void k_gemm2(const __half* __restrict__ A, const f16x8* __restrict__ Wfrag,
                        __half* __restrict__ h2h, const float* __restrict__ a_src,
                        const float* __restrict__ a_dst, float* __restrict__ es,
                        float* __restrict__ ed, int n) {
    __shared__ __align__(16) __half sm[64 * LDA2];
    int tid = threadIdx.x, lane = tid & 63, w = tid >> 6;
    int row0 = blockIdx.x * 64;

    f16x8 bf[8][2];
#pragma unroll
    for (int kc = 0; kc < 8; kc++)
#pragma unroll
        for (int cc = 0; cc < 2; cc++)
            bf[kc][cc] = Wfrag[(kc * 2 + cc) * 64 + lane];

    for (int i = tid; i < 64 * 32; i += 256) {
        int r = i >> 5, cb = i & 31;
        uint4 u = make_uint4(0, 0, 0, 0);
        if (row0 + r < n) u = *(const uint4*)(A + (size_t)(row0 + r) * 256 + cb * 8);
        *(uint4*)(sm + r * LDA2 + cb * 8) = u;
    }
    __syncthreads();

    f32x4 acc[2];
    acc[0] = (f32x4){0.f, 0.f, 0.f, 0.f};
    acc[1] = (f32x4){0.f, 0.f, 0.f, 0.f};
    int arow = w * 16 + (lane & 15);
#pragma unroll
    for (int kc = 0; kc < 8; kc++) {
        f16x8 af = *(const f16x8*)(sm + arow * LDA2 + kc * 32 + ((lane >> 4) << 3));
#pragma unroll
        for (int cc = 0; cc < 2; cc++)
            acc[cc] = __builtin_amdgcn_mfma_f32_16x16x32_f16(af, bf[kc][cc], acc[cc], 0, 0, 0);
    }
    int gr0 = row0 + w * 16 + ((lane >> 4) << 2);
#pragma unroll
    for (int cc = 0; cc < 2; cc++) {
        int colp = cc * 16 + (lane & 15);
#pragma unroll
        for (int j = 0; j < 4; j++) {
            int gr = gr0 + j;
            if (gr < n) h2h[(size_t)gr * 32 + colp] = __float2half(acc[cc][j]);
        }
    }
    // fused att2
    float as0 = a_src[lane & 15], as1 = a_src[16 + (lane & 15)];
    float ad0 = a_dst[lane & 15], ad1 = a_dst[16 + (lane & 15)];
#pragma unroll
    for (int j = 0; j < 4; j++) {
        float ps = acc[0][j] * as0 + acc[1][j] * as1;
        float pd = acc[0][j] * ad0 + acc[1][j] * ad1;
#pragma unroll
        for (int off = 1; off < 16; off <<= 1) {
            ps += __shfl_xor(ps, off);
            pd += __shfl_xor(pd, off);
        }
        int gr = gr0 + j;
        if ((lane & 15) == 0 && gr < n) {
            es[gr] = ps;
            ed[gr] = pd;
        }
    }
}

// ---------------- layer2 aggregation: 16-lane groups, 8 edges/iter (2-deep MLP) ----------------
__global__ void k_aggr2(const __half* __restrict__ h2h, const float* __restrict__ es,
                        const float* __restrict__ ed, const int* __restrict__ row_ptr,
                        const int* __restrict__ col, const float* __restrict__ b,
                        float* __restrict__ emb, int n) {
    __shared__ int s_idx[4][64];
    __shared__ float s_a[4][64];
    int tid = threadIdx.x, lane = tid & 63, w = tid >> 6;
    int node = blockIdx.x * 4 + w;
    if (node >= n) return;
    const uint* h2u = (const uint*)h2h;
    float edv = ed[node];
    float selft = __expf(leaky(es[node] + edv));
    int q = lane >> 4, cpair = lane & 15;
    uint sraw = h2u[(size_t)node * 16 + cpair];
    __half2 sh = *reinterpret_cast<__half2*>(&sraw);
    float acc0 = (q == 0) ? selft * __half2float(sh.x) : 0.f;
    float acc1 = (q == 0) ? selft * __half2float(sh.y) : 0.f;
    float dl = (lane == 0) ? selft : 0.f;
    int beg = row_ptr[node], end = row_ptr[node + 1];
    for (int base = beg; base < end; base += 64) {
        int nv = end - base;
        if (nv > 64) nv = 64;
        int j = base + lane;
        int s = 0;
        float exl = 0.f;
        if (j < end) {
            s = col[j];
            exl = __expf(leaky(es[s] + edv));
            dl += exl;
        }
        s_idx[w][lane] = s;
        s_a[w][lane] = exl;
        for (int j2 = 0; j2 < nv; j2 += 8) {
            int jj0 = j2 + q, jj1 = j2 + 4 + q;
            bool v0 = jj0 < nv, v1 = jj1 < nv;
            int sb0 = v0 ? s_idx[w][jj0] : 0;
            float a0 = v0 ? s_a[w][jj0] : 0.f;
            int sb1 = v1 ? s_idx[w][jj1] : 0;
            float a1 = v1 ? s_a[w][jj1] : 0.f;
            uint r0 = h2u[(size_t)sb0 * 16 + cpair];
            uint r1 = h2u[(size_t)sb1 * 16 + cpair];
            __half2 p0 = *reinterpret_cast<__half2*>(&r0);
            __half2 p1 = *reinterpret_cast<__half2*>(&r1);
            acc0 += a0 * __half2float(p0.x) + a1 * __half2float(p1.x);
            acc1 += a0 * __half2float(p0.y) + a1 * __half2float(p1.y);
        }
    }
    acc0 += __shfl_xor(acc0, 16);
    acc0 += __shfl_xor(acc0, 32);
    acc1 += __shfl_xor(acc1, 16);
    acc1 += __shfl_xor(acc1, 32);
#pragma unroll
    for (int off = 32; off; off >>= 1) dl += __shfl_xor(dl, off);
    if (lane < 16) {
        float inv = 1.f / (dl + 1e-16f);
        float2 bv = ((const float2*)b)[cpair];
        float2 o;
        o.x = acc0 * inv + bv.x;
        o.y = acc1 * inv + bv.y;
        *(float2*)(emb + (size_t)node * 32 + cpair * 2) = o;
    }
}

extern "C" void kernel_launch(void* const* d_in, const int* in_sizes, int n_in,
                              void* d_out, int out_size, void* d_ws, size_t ws_size,
                              hipStream_t stream) {
    const float* x = (const float*)d_in[0];
    const int* edge_index = (const int*)d_in[1];
    const float* W1 = (const float*)d_in[2];
    const float* a_src1 = (const float*)d_in[3];
    const float* a_dst1 = (const float*)d_in[4];
    const float* b1 = (const float*)d_in[5];
    const float* W2 = (const float*)d_in[6];
    const float* a_src2 = (const float*)d_in[7];
    const float* a_dst2 = (const float*)d_in[8];
    const float* b2 = (const float*)d_in[9];
    float* emb = (float*)d_out;

    const int* src = edge_index;
    const int* dst = edge_index + N_EDGES;

    char* w = (char*)d_ws;
    auto alloc = [&](size_t bytes) {
        char* p = w;
        w += (bytes + 255) & ~(size_t)255;
        return (void*)p;
    };
    int* row_ptr = (int*)alloc((N_NODES + 1) * 4);
    int* col = (int*)alloc((size_t)N_EDGES * 4);
    int* partT = (int*)alloc((size_t)NBKT * NCHUNK * 4);  // 1 MB, bucket-major
    int* part2 = (int*)alloc((size_t)NCHUNK * NBKT * 4);  // 1 MB, chunk-major offsets
    int* bucket_base = (int*)alloc((NBKT + 1) * 4);
    uint* ebuf = (uint*)alloc((size_t)N_EDGES * 4);       // 6.4 MB
    __half* h1h = (__half*)alloc((size_t)N_NODES * C1 * 2);
    float* es1 = (float*)alloc(N_NODES * HEADS * 4);
    float* ed1 = (float*)alloc(N_NODES * HEADS * 4);
    __half* out1h = (__half*)alloc((size_t)N_NODES * C1 * 2);
    __half* h2h = (__half*)alloc((size_t)N_NODES * OUT_DIM * 2);
    float* es2 = (float*)alloc(N_NODES * 4);
    float* ed2 = (float*)alloc(N_NODES * 4);
    f16x8* W1fr = (f16x8*)alloc(4096 * 16);  // 64 KB
    f16x8* W2fr = (f16x8*)alloc(1024 * 16);  // 16 KB

    // bucketed CSR build (no global atomics); wfrag fused into bhist's grid
    k_bhist<<<NCHUNK + 20, 256, 0, stream>>>(dst, partT, W1, W2, W1fr, W2fr);
    k_bscan<<<1, NBKT, 0, stream>>>(partT, part2, bucket_base, row_ptr + N_NODES);
    k_bscatter<<<NCHUNK, 256, 0, stream>>>(src, dst, part2, ebuf);
    k_bsort<<<NBKT_USED, 256, 0, stream>>>(ebuf, bucket_base, row_ptr, col, N_NODES);

    // layer 1
    k_gemm1<<<(N_NODES + 63) / 64, 256, 0, stream>>>(x, W1fr, h1h, a_src1, a_dst1, es1, ed1,
                                                     N_NODES);
    k_aggr1<<<(N_NODES + 7) / 8, 256, 0, stream>>>(h1h, es1, ed1, row_ptr, col, b1, out1h,
                                                   N_NODES);

    // layer 2
    k_gemm2<<<(N_NODES + 63) / 64, 256, 0, stream>>>(out1h, W2fr, h2h, a_src2, a_dst2, es2, ed2,
                                                     N_NODES);
    k_aggr2<<<(N_NODES + 3) / 4, 256, 0, stream>>>(h2h, es2, ed2, row_ptr, col, b2, emb, N_NODES);
}

// Round 10
// 306.562 us; speedup vs baseline: 1.1292x; 1.1292x over previous
//
#include <hip/hip_runtime.h>
#include <hip/hip_bf16.h>
#include <hip/hip_fp16.h>

#define N_NODES 100000
#define N_EDGES 1600000
#define IN_DIM 128
#define C1 256      // HEADS*HID = 4*64
#define HID 64
#define HEADS 4
#define OUT_DIM 32
#define SLOPE 0.2f

// bucketed CSR build params
#define NCHUNK 256
#define CHUNK_E ((N_EDGES + NCHUNK - 1) / NCHUNK)  // 6250
#define NBKT 1024        // buckets of 128 nodes (782 used)
#define BSH 7
#define NBKT_USED ((N_NODES + 127) >> 7)  // 782

typedef _Float16 f16x8 __attribute__((ext_vector_type(8)));
typedef float f32x4 __attribute__((ext_vector_type(4)));

__device__ __forceinline__ float leaky(float t) { return t > 0.f ? t : SLOPE * t; }

__device__ __forceinline__ float sel4(float a, float b, float c, float d, int k) {
    float lo = (k & 1) ? b : a;
    float hi = (k & 1) ? d : c;
    return (k & 2) ? hi : lo;
}

// ---------------- bucketed CSR build (LDS atomics only) ----------------
// part[chunk][bucket]: at any loop iteration, a wave's lanes (consecutive bucket
// index) touch contiguous addresses -> coalesced. (Round-9 bucket-major layout
// broke this: coalescing is per-instruction across lanes, not per-thread.)
// Blocks >= NCHUNK handle the W1/W2 fragment repack (fused to save a dispatch).
__global__ void k_bhist(const int* __restrict__ dst, int* __restrict__ part,
                        const float* __restrict__ W1, const float* __restrict__ W2,
                        f16x8* __restrict__ o1, f16x8* __restrict__ o2) {
    int blk = blockIdx.x, tid = threadIdx.x;
    if (blk >= NCHUNK) {
        int t = (blk - NCHUNK) * 256 + tid;
        if (t < 4096) {
            int kc = t >> 10, c = (t >> 6) & 15, lane = t & 63;
            int k0 = kc * 32 + ((lane >> 4) << 3), nn = c * 16 + (lane & 15);
            f16x8 r;
#pragma unroll
            for (int v = 0; v < 8; v++) r[v] = (_Float16)W1[(k0 + v) * 256 + nn];
            o1[t] = r;
        } else if (t < 5120) {
            int u = t - 4096;
            int kc = u >> 7, c = (u >> 6) & 1, lane = u & 63;
            int k0 = kc * 32 + ((lane >> 4) << 3), nn = c * 16 + (lane & 15);
            f16x8 r;
#pragma unroll
            for (int v = 0; v < 8; v++) r[v] = (_Float16)W2[(k0 + v) * 32 + nn];
            o2[u] = r;
        }
        return;
    }
    __shared__ int h[NBKT];
    for (int i = tid; i < NBKT; i += 256) h[i] = 0;
    __syncthreads();
    int e0 = blk * CHUNK_E;
    int e1 = e0 + CHUNK_E;
    if (e1 > N_EDGES) e1 = N_EDGES;
    for (int i = e0 + tid; i < e1; i += 256) atomicAdd(&h[dst[i] >> BSH], 1);
    __syncthreads();
    for (int i = tid; i < NBKT; i += 256) part[blk * NBKT + i] = h[i];
}

// single block, 1024 threads; lanes coalesced at every iteration (fixed c)
__global__ void k_bscan(int* __restrict__ part, int* __restrict__ bucket_base,
                        int* __restrict__ row_ptr_last) {
    __shared__ int sm[NBKT];
    int b = threadIdx.x;
    int tot = 0;
    for (int c = 0; c < NCHUNK; c++) tot += part[c * NBKT + b];
    sm[b] = tot;
    __syncthreads();
    for (int off = 1; off < NBKT; off <<= 1) {
        int u = (b >= off) ? sm[b - off] : 0;
        __syncthreads();
        sm[b] += u;
        __syncthreads();
    }
    int incl = sm[b], excl = incl - tot;
    bucket_base[b] = excl;
    if (b == NBKT - 1) {
        bucket_base[NBKT] = incl;
        *row_ptr_last = incl;  // row_ptr[N] = E
    }
    int run = excl;
    for (int c = 0; c < NCHUNK; c++) {
        int idx = c * NBKT + b;
        int v = part[idx];
        part[idx] = run;
        run += v;
    }
}

__global__ void k_bscatter(const int* __restrict__ src, const int* __restrict__ dst,
                           const int* __restrict__ part, uint* __restrict__ ebuf) {
    __shared__ int cur[NBKT];
    int tid = threadIdx.x, blk = blockIdx.x;
    for (int i = tid; i < NBKT; i += 256) cur[i] = part[blk * NBKT + i];
    __syncthreads();
    int e0 = blk * CHUNK_E;
    int e1 = e0 + CHUNK_E;
    if (e1 > N_EDGES) e1 = N_EDGES;
    for (int i = e0 + tid; i < e1; i += 256) {
        int d = dst[i];
        int b = d >> BSH;
        int pos = atomicAdd(&cur[b], 1);
        ebuf[pos] = (uint)src[i] | ((uint)(d & 127) << 20);
    }
}

__global__ void k_bsort(const uint* __restrict__ ebuf, const int* __restrict__ bucket_base,
                        int* __restrict__ row_ptr, int* __restrict__ col, int n) {
    __shared__ int h[128], sc[128], cur[128];
    int tid = threadIdx.x, b = blockIdx.x;
    int s0 = bucket_base[b], s1 = bucket_base[b + 1];
    if (tid < 128) h[tid] = 0;
    __syncthreads();
    for (int i = s0 + tid; i < s1; i += 256) atomicAdd(&h[ebuf[i] >> 20], 1);
    __syncthreads();
    if (tid < 128) sc[tid] = h[tid];
    __syncthreads();
    for (int off = 1; off < 128; off <<= 1) {
        int u = 0;
        if (tid < 128 && tid >= off) u = sc[tid - off];
        __syncthreads();
        if (tid < 128) sc[tid] += u;
        __syncthreads();
    }
    if (tid < 128) {
        int excl = sc[tid] - h[tid];
        cur[tid] = excl;
        int node = (b << BSH) + tid;
        if (node < n) row_ptr[node] = s0 + excl;
    }
    __syncthreads();
    for (int i = s0 + tid; i < s1; i += 256) {
        uint pk = ebuf[i];
        int f = pk >> 20;
        int pos = atomicAdd(&cur[f], 1);
        col[s0 + pos] = (int)(pk & 0xFFFFFu);
    }
}

// ---------------- GEMM1 (MFMA) + fused att1 ----------------
#define LDA 136
#define LDO 264
__launch_bounds__(256)
__global__ void k_gemm1(const float* __restrict__ x, const f16x8* __restrict__ Wfrag,
                        __half* __restrict__ h1h, const float* __restrict__ a_src,
                        const float* __restrict__ a_dst, float* __restrict__ es,
                        float* __restrict__ ed, int n) {
    __shared__ __align__(16) __half sm[64 * LDO];
    __shared__ float s_es[4][64], s_ed[4][64];
    int tid = threadIdx.x, lane = tid & 63, w = tid >> 6;
    int row0 = blockIdx.x * 64;

    f16x8 bf[4][4];
#pragma unroll
    for (int kc = 0; kc < 4; kc++)
#pragma unroll
        for (int cc = 0; cc < 4; cc++)
            bf[kc][cc] = Wfrag[(kc * 16 + w * 4 + cc) * 64 + lane];

    for (int i = tid; i < 64 * 32; i += 256) {
        int r = i >> 5, c4 = i & 31;
        float4 v = make_float4(0.f, 0.f, 0.f, 0.f);
        if (row0 + r < n) v = *(const float4*)(x + (size_t)(row0 + r) * 128 + c4 * 4);
        __half2 h0 = __halves2half2(__float2half(v.x), __float2half(v.y));
        __half2 h1 = __halves2half2(__float2half(v.z), __float2half(v.w));
        uint2 u;
        u.x = *(uint*)&h0;
        u.y = *(uint*)&h1;
        *(uint2*)(sm + r * LDA + c4 * 4) = u;
    }
    __syncthreads();

    f32x4 acc[4][4];
#pragma unroll
    for (int rf = 0; rf < 4; rf++)
#pragma unroll
        for (int cc = 0; cc < 4; cc++) acc[rf][cc] = (f32x4){0.f, 0.f, 0.f, 0.f};

#pragma unroll
    for (int kc = 0; kc < 4; kc++) {
        f16x8 af[4];
#pragma unroll
        for (int rf = 0; rf < 4; rf++) {
            int row = rf * 16 + (lane & 15);
            int koff = kc * 32 + ((lane >> 4) << 3);
            af[rf] = *(const f16x8*)(sm + row * LDA + koff);
        }
#pragma unroll
        for (int rf = 0; rf < 4; rf++)
#pragma unroll
            for (int cc = 0; cc < 4; cc++)
                acc[rf][cc] = __builtin_amdgcn_mfma_f32_16x16x32_f16(af[rf], bf[kc][cc],
                                                                     acc[rf][cc], 0, 0, 0);
    }
    __syncthreads();

#pragma unroll
    for (int rf = 0; rf < 4; rf++)
#pragma unroll
        for (int cc = 0; cc < 4; cc++) {
            int colp = w * 64 + cc * 16 + (lane & 15);
            int rb = rf * 16 + ((lane >> 4) << 2);
#pragma unroll
            for (int j = 0; j < 4; j++) sm[(rb + j) * LDO + colp] = __float2half(acc[rf][cc][j]);
        }
    __syncthreads();

    // fused att1: thread handles (row = tid&63, head q = tid>>6)
    {
        int row = tid & 63, q = w;
        float ps = 0.f, pd = 0.f;
        const __half* rp = sm + row * LDO + q * 64;
#pragma unroll
        for (int c4 = 0; c4 < 16; c4++) {
            uint2 u = *(const uint2*)(rp + c4 * 4);
            __half2 ha = *reinterpret_cast<__half2*>(&u.x);
            __half2 hb = *reinterpret_cast<__half2*>(&u.y);
            float v0 = __half2float(ha.x), v1 = __half2float(ha.y);
            float v2 = __half2float(hb.x), v3 = __half2float(hb.y);
            float4 av = *(const float4*)(a_src + q * 64 + c4 * 4);
            float4 dv = *(const float4*)(a_dst + q * 64 + c4 * 4);
            ps += v0 * av.x + v1 * av.y + v2 * av.z + v3 * av.w;
            pd += v0 * dv.x + v1 * dv.y + v2 * dv.z + v3 * dv.w;
        }
        s_es[q][row] = ps;
        s_ed[q][row] = pd;
    }

    for (int i = tid; i < 64 * 32; i += 256) {
        int r = i >> 5, cb = i & 31;
        if (row0 + r < n) {
            uint4 u = *(const uint4*)(sm + r * LDO + cb * 8);
            *(uint4*)(h1h + (size_t)(row0 + r) * 256 + cb * 8) = u;
        }
    }
    __syncthreads();
    if (tid < 64 && row0 + tid < n) {
        ((float4*)es)[row0 + tid] =
            make_float4(s_es[0][tid], s_es[1][tid], s_es[2][tid], s_es[3][tid]);
        ((float4*)ed)[row0 + tid] =
            make_float4(s_ed[0][tid], s_ed[1][tid], s_ed[2][tid], s_ed[3][tid]);
    }
}

// ---------------- layer1 aggregation: 32 lanes per node, 2 nodes per wave, 4-deep MLP ----------------
__launch_bounds__(256)
__global__ void k_aggr1(const __half* __restrict__ h1h, const float* __restrict__ es,
                        const float* __restrict__ ed, const int* __restrict__ row_ptr,
                        const int* __restrict__ col, const float* __restrict__ b,
                        __half* __restrict__ out1h, int n) {
    __shared__ int s_idx[4][64];
    __shared__ __align__(16) float s_al[4][256];
    int tid = threadIdx.x, lane = tid & 63, w = tid >> 6;
    int h = lane >> 5, l = lane & 31, k0 = l >> 3;
    int node = blockIdx.x * 8 + w * 2 + h;
    bool valid = node < n;
    int nodec = valid ? node : 0;

    float4 ed4 = ((const float4*)ed)[nodec];
    float4 es4 = ((const float4*)es)[nodec];
    float edk = sel4(ed4.x, ed4.y, ed4.z, ed4.w, k0);
    float esk = sel4(es4.x, es4.y, es4.z, es4.w, k0);

    uint4 sraw = *(const uint4*)(h1h + (size_t)nodec * 256 + l * 8);
    const __half2* sh = (const __half2*)&sraw;
    float tself = __expf(leaky(esk + edk));
    float acc[8];
#pragma unroll
    for (int i = 0; i < 4; i++) {
        acc[2 * i] = tself * __half2float(sh[i].x);
        acc[2 * i + 1] = tself * __half2float(sh[i].y);
    }
    float dl[4];
#pragma unroll
    for (int k = 0; k < 4; k++) dl[k] = 0.f;
    if (l == 0) {
        dl[0] = __expf(leaky(es4.x + ed4.x));
        dl[1] = __expf(leaky(es4.y + ed4.y));
        dl[2] = __expf(leaky(es4.z + ed4.z));
        dl[3] = __expf(leaky(es4.w + ed4.w));
    }

    int beg = valid ? row_ptr[nodec] : 0;
    int end = valid ? row_ptr[nodec + 1] : 0;
    int deg = end - beg;
    for (int base = 0;; base += 32) {
        int rem = deg - base;
        int nvh = rem > 32 ? 32 : rem;
        int nvo = __shfl_xor(nvh < 0 ? 0 : nvh, 32);
        int nvmax = nvh > nvo ? nvh : nvo;
        if (nvmax <= 0) break;
        int j = beg + base + l;
        int s = 0;
        float e0 = 0.f, e1 = 0.f, e2 = 0.f, e3 = 0.f;
        if (l < nvh) {
            s = col[j];
            float4 e4 = ((const float4*)es)[s];
            e0 = __expf(leaky(e4.x + ed4.x));
            e1 = __expf(leaky(e4.y + ed4.y));
            e2 = __expf(leaky(e4.z + ed4.z));
            e3 = __expf(leaky(e4.w + ed4.w));
            dl[0] += e0;
            dl[1] += e1;
            dl[2] += e2;
            dl[3] += e3;
        }
        s_idx[w][lane] = s;
        *(float4*)&s_al[w][lane * 4] = make_float4(e0, e1, e2, e3);
        int lbase = h << 5;
        // 4-deep batched gather: issue 4 independent loads before consuming
        for (int j2 = 0; j2 < nvmax; j2 += 4) {
            int sb[4];
            float ee[4];
#pragma unroll
            for (int u = 0; u < 4; u++) {
                int jj = j2 + u;
                bool v2 = jj < nvh;
                sb[u] = v2 ? s_idx[w][lbase + jj] : 0;
                ee[u] = v2 ? s_al[w][(lbase + jj) * 4 + k0] : 0.f;
            }
            uint4 rv0 = *(const uint4*)(h1h + (size_t)sb[0] * 256 + l * 8);
            uint4 rv1 = *(const uint4*)(h1h + (size_t)sb[1] * 256 + l * 8);
            uint4 rv2 = *(const uint4*)(h1h + (size_t)sb[2] * 256 + l * 8);
            uint4 rv3 = *(const uint4*)(h1h + (size_t)sb[3] * 256 + l * 8);
            uint4 rvs[4] = {rv0, rv1, rv2, rv3};
#pragma unroll
            for (int u = 0; u < 4; u++) {
                const __half2* hp = (const __half2*)&rvs[u];
                float e = ee[u];
#pragma unroll
                for (int i = 0; i < 4; i++) {
                    acc[2 * i] += e * __half2float(hp[i].x);
                    acc[2 * i + 1] += e * __half2float(hp[i].y);
                }
            }
        }
    }
#pragma unroll
    for (int off = 1; off < 32; off <<= 1) {
#pragma unroll
        for (int k = 0; k < 4; k++) dl[k] += __shfl_xor(dl[k], off);
    }
    float dlk = sel4(dl[0], dl[1], dl[2], dl[3], k0) + 1e-16f;
    float inv = 1.f / dlk;
    float4 b0 = *(const float4*)(b + l * 8);
    float4 b1 = *(const float4*)(b + l * 8 + 4);
    float o[8];
    o[0] = acc[0] * inv + b0.x;
    o[1] = acc[1] * inv + b0.y;
    o[2] = acc[2] * inv + b0.z;
    o[3] = acc[3] * inv + b0.w;
    o[4] = acc[4] * inv + b1.x;
    o[5] = acc[5] * inv + b1.y;
    o[6] = acc[6] * inv + b1.z;
    o[7] = acc[7] * inv + b1.w;
    uint4 pk;
    __half2* ph = (__half2*)&pk;
#pragma unroll
    for (int i = 0; i < 4; i++) {
        float a0 = o[2 * i], a1 = o[2 * i + 1];
        a0 = a0 > 0.f ? a0 : __expf(a0) - 1.f;
        a1 = a1 > 0.f ? a1 : __expf(a1) - 1.f;
        ph[i] = __halves2half2(__float2half(a0), __float2half(a1));
    }
    if (valid) *(uint4*)(out1h + (size_t)node * 256 + l * 8) = pk;
}

// ---------------- GEMM2 (MFMA) + fused att2 ----------------
#define LDA2 264
__launch_bounds__(256)
__global__ void k_gemm2(const __half* __restrict__ A, const f16x8* __restrict__ Wfrag,
                        __half* __restrict__ h2h, const float* __restrict__ a_src,
                        const float* __restrict__ a_dst, float* __restrict__ es,
                        float* __restrict__ ed, int n) {
    __shared__ __align__(16) __half sm[64 * LDA2];
    int tid = threadIdx.x, lane = tid & 63, w = tid >> 6;
    int row0 = blockIdx.x * 64;

    f16x8 bf[8][2];
#pragma unroll
    for (int kc = 0; kc < 8; kc++)
#pragma unroll
        for (int cc = 0; cc < 2; cc++)
            bf[kc][cc] = Wfrag[(kc * 2 + cc) * 64 + lane];

    for (int i = tid; i < 64 * 32; i += 256) {
        int r = i >> 5, cb = i & 31;
        uint4 u = make_uint4(0, 0, 0, 0);
        if (row0 + r < n) u = *(const uint4*)(A + (size_t)(row0 + r) * 256 + cb * 8);
        *(uint4*)(sm + r * LDA2 + cb * 8) = u;
    }
    __syncthreads();

    f32x4 acc[2];
    acc[0] = (f32x4){0.f, 0.f, 0.f, 0.f};
    acc[1] = (f32x4){0.f, 0.f, 0.f, 0.f};
    int arow = w * 16 + (lane & 15);
#pragma unroll
    for (int kc = 0; kc < 8; kc++) {
        f16x8 af = *(const f16x8*)(sm + arow * LDA2 + kc * 32 + ((lane >> 4) << 3));
#pragma unroll
        for (int cc = 0; cc < 2; cc++)
            acc[cc] = __builtin_amdgcn_mfma_f32_16x16x32_f16(af, bf[kc][cc], acc[cc], 0, 0, 0);
    }
    int gr0 = row0 + w * 16 + ((lane >> 4) << 2);
#pragma unroll
    for (int cc = 0; cc < 2; cc++) {
        int colp = cc * 16 + (lane & 15);
#pragma unroll
        for (int j = 0; j < 4; j++) {
            int gr = gr0 + j;
            if (gr < n) h2h[(size_t)gr * 32 + colp] = __float2half(acc[cc][j]);
        }
    }
    // fused att2
    float as0 = a_src[lane & 15], as1 = a_src[16 + (lane & 15)];
    float ad0 = a_dst[lane & 15], ad1 = a_dst[16 + (lane & 15)];
#pragma unroll
    for (int j = 0; j < 4; j++) {
        float ps = acc[0][j] * as0 + acc[1][j] * as1;
        float pd = acc[0][j] * ad0 + acc[1][j] * ad1;
#pragma unroll
        for (int off = 1; off < 16; off <<= 1) {
            ps += __shfl_xor(ps, off);
            pd += __shfl_xor(pd, off);
        }
        int gr = gr0 + j;
        if ((lane & 15) == 0 && gr < n) {
            es[gr] = ps;
            ed[gr] = pd;
        }
    }
}

// ---------------- layer2 aggregation: 16-lane groups, 8 edges/iter (2-deep MLP) ----------------
__global__ void k_aggr2(const __half* __restrict__ h2h, const float* __restrict__ es,
                        const float* __restrict__ ed, const int* __restrict__ row_ptr,
                        const int* __restrict__ col, const float* __restrict__ b,
                        float* __restrict__ emb, int n) {
    __shared__ int s_idx[4][64];
    __shared__ float s_a[4][64];
    int tid = threadIdx.x, lane = tid & 63, w = tid >> 6;
    int node = blockIdx.x * 4 + w;
    if (node >= n) return;
    const uint* h2u = (const uint*)h2h;
    float edv = ed[node];
    float selft = __expf(leaky(es[node] + edv));
    int q = lane >> 4, cpair = lane & 15;
    uint sraw = h2u[(size_t)node * 16 + cpair];
    __half2 sh = *reinterpret_cast<__half2*>(&sraw);
    float acc0 = (q == 0) ? selft * __half2float(sh.x) : 0.f;
    float acc1 = (q == 0) ? selft * __half2float(sh.y) : 0.f;
    float dl = (lane == 0) ? selft : 0.f;
    int beg = row_ptr[node], end = row_ptr[node + 1];
    for (int base = beg; base < end; base += 64) {
        int nv = end - base;
        if (nv > 64) nv = 64;
        int j = base + lane;
        int s = 0;
        float exl = 0.f;
        if (j < end) {
            s = col[j];
            exl = __expf(leaky(es[s] + edv));
            dl += exl;
        }
        s_idx[w][lane] = s;
        s_a[w][lane] = exl;
        for (int j2 = 0; j2 < nv; j2 += 8) {
            int jj0 = j2 + q, jj1 = j2 + 4 + q;
            bool v0 = jj0 < nv, v1 = jj1 < nv;
            int sb0 = v0 ? s_idx[w][jj0] : 0;
            float a0 = v0 ? s_a[w][jj0] : 0.f;
            int sb1 = v1 ? s_idx[w][jj1] : 0;
            float a1 = v1 ? s_a[w][jj1] : 0.f;
            uint r0 = h2u[(size_t)sb0 * 16 + cpair];
            uint r1 = h2u[(size_t)sb1 * 16 + cpair];
            __half2 p0 = *reinterpret_cast<__half2*>(&r0);
            __half2 p1 = *reinterpret_cast<__half2*>(&r1);
            acc0 += a0 * __half2float(p0.x) + a1 * __half2float(p1.x);
            acc1 += a0 * __half2float(p0.y) + a1 * __half2float(p1.y);
        }
    }
    acc0 += __shfl_xor(acc0, 16);
    acc0 += __shfl_xor(acc0, 32);
    acc1 += __shfl_xor(acc1, 16);
    acc1 += __shfl_xor(acc1, 32);
#pragma unroll
    for (int off = 32; off; off >>= 1) dl += __shfl_xor(dl, off);
    if (lane < 16) {
        float inv = 1.f / (dl + 1e-16f);
        float2 bv = ((const float2*)b)[cpair];
        float2 o;
        o.x = acc0 * inv + bv.x;
        o.y = acc1 * inv + bv.y;
        *(float2*)(emb + (size_t)node * 32 + cpair * 2) = o;
    }
}

extern "C" void kernel_launch(void* const* d_in, const int* in_sizes, int n_in,
                              void* d_out, int out_size, void* d_ws, size_t ws_size,
                              hipStream_t stream) {
    const float* x = (const float*)d_in[0];
    const int* edge_index = (const int*)d_in[1];
    const float* W1 = (const float*)d_in[2];
    const float* a_src1 = (const float*)d_in[3];
    const float* a_dst1 = (const float*)d_in[4];
    const float* b1 = (const float*)d_in[5];
    const float* W2 = (const float*)d_in[6];
    const float* a_src2 = (const float*)d_in[7];
    const float* a_dst2 = (const float*)d_in[8];
    const float* b2 = (const float*)d_in[9];
    float* emb = (float*)d_out;

    const int* src = edge_index;
    const int* dst = edge_index + N_EDGES;

    char* w = (char*)d_ws;
    auto alloc = [&](size_t bytes) {
        char* p = w;
        w += (bytes + 255) & ~(size_t)255;
        return (void*)p;
    };
    int* row_ptr = (int*)alloc((N_NODES + 1) * 4);
    int* col = (int*)alloc((size_t)N_EDGES * 4);
    int* part = (int*)alloc((size_t)NCHUNK * NBKT * 4);   // 1 MB, chunk-major
    int* bucket_base = (int*)alloc((NBKT + 1) * 4);
    uint* ebuf = (uint*)alloc((size_t)N_EDGES * 4);       // 6.4 MB
    __half* h1h = (__half*)alloc((size_t)N_NODES * C1 * 2);
    float* es1 = (float*)alloc(N_NODES * HEADS * 4);
    float* ed1 = (float*)alloc(N_NODES * HEADS * 4);
    __half* out1h = (__half*)alloc((size_t)N_NODES * C1 * 2);
    __half* h2h = (__half*)alloc((size_t)N_NODES * OUT_DIM * 2);
    float* es2 = (float*)alloc(N_NODES * 4);
    float* ed2 = (float*)alloc(N_NODES * 4);
    f16x8* W1fr = (f16x8*)alloc(4096 * 16);  // 64 KB
    f16x8* W2fr = (f16x8*)alloc(1024 * 16);  // 16 KB

    // bucketed CSR build (no global atomics); wfrag fused into bhist's grid
    k_bhist<<<NCHUNK + 20, 256, 0, stream>>>(dst, part, W1, W2, W1fr, W2fr);
    k_bscan<<<1, NBKT, 0, stream>>>(part, bucket_base, row_ptr + N_NODES);
    k_bscatter<<<NCHUNK, 256, 0, stream>>>(src, dst, part, ebuf);
    k_bsort<<<NBKT_USED, 256, 0, stream>>>(ebuf, bucket_base, row_ptr, col, N_NODES);

    // layer 1
    k_gemm1<<<(N_NODES + 63) / 64, 256, 0, stream>>>(x, W1fr, h1h, a_src1, a_dst1, es1, ed1,
                                                     N_NODES);
    k_aggr1<<<(N_NODES + 7) / 8, 256, 0, stream>>>(h1h, es1, ed1, row_ptr, col, b1, out1h,
                                                   N_NODES);

    // layer 2
    k_gemm2<<<(N_NODES + 63) / 64, 256, 0, stream>>>(out1h, W2fr, h2h, a_src2, a_dst2, es2, ed2,
                                                     N_NODES);
    k_aggr2<<<(N_NODES + 3) / 4, 256, 0, stream>>>(h2h, es2, ed2, row_ptr, col, b2, emb, N_NODES);
}